// Round 6
// baseline (196.270 us; speedup 1.0000x reference)
//
#include <hip/hip_runtime.h>
#include <hip/hip_fp16.h>

// GNNDecoder: out = relu((einsum("nk,nkl->nl", s, z[batch])) @ W1 + b1) @ W2 + b2
// N=100000, B=256, K=32, LATENT=64, HIDDEN=256, OUT=32. fp32 in/out.
//
// R5 post-mortem: kernel is request-rate bound on the z-gather (~200k
// line-requests/CU ~= 80us): every node re-reads its whole 8KB z[b] with
// per-lane 16B loads to distinct lines; 800MB L2 traffic for a 2MB table.
// R6: bucket nodes by graph (count/scan/scatter into d_ws), each decoder
// block = 64 nodes of ONE graph -> z[b] staged once (traffic -> ~15MB) and
// phase 0b becomes one MFMA per l-tile (lat = s@z[b], K=32). D->B-frag
// transpose via 2KB/wave LDS round-trip; R5's verified stage-A/B pipeline
// kept verbatim. LDS 22KB -> 7 blocks/CU, ONE __syncthreads total.
// Frag maps (HW-verified R4/R5): A[m=lane&15][k=quad*8+j],
// B[k=quad*8+j][n=lane&15], C/D col=lane&15 row=quad*4+reg.

using f16   = _Float16;
using f16x4 = __attribute__((ext_vector_type(4))) _Float16;
using f16x8 = __attribute__((ext_vector_type(8))) _Float16;
using f32x4 = __attribute__((ext_vector_type(4))) float;

constexpr int NN     = 100000;
constexpr int KK     = 32;
constexpr int LATENT = 64;
constexpr int HIDDEN = 256;
constexpr int OUTD   = 32;

constexpr int BLOCK    = 256;   // 4 waves, 16 nodes/wave
constexpr int DESC_MAX = 1819;  // sum ceil(cnt/64) <= 1563 + 255

// d_ws layout: [0,48K) f16 weights; then cnt[256], cursor[256], desc[2048],
// perm[100000] (ints). Total ~459 KB.
constexpr int W2F_OFF = 16384;  // f16 index

__global__ void convert_weights(const float* __restrict__ W1,
                                const float* __restrict__ W2,
                                f16* __restrict__ wsf,
                                int* __restrict__ cnt) {
    const int tid = blockIdx.x * blockDim.x + threadIdx.x;
    if (tid < 256) cnt[tid] = 0;                       // zero bucket counters
    if (tid < 16384) {
        const int j = tid & 7, lane = (tid >> 3) & 63, g = tid >> 9;
        const int ks = g & 1, nt = g >> 1;
        const int k = ks * 32 + (lane >> 4) * 8 + j;   // latent
        const int c = nt * 16 + (lane & 15);           // hidden
        wsf[tid] = (f16)W1[k * HIDDEN + c];            // A-frag for stage A
    } else if (tid < 16384 + 8192) {
        const int tid2 = tid - 16384;
        const int j = tid2 & 7, lane = (tid2 >> 3) & 63, g = tid2 >> 9;
        const int ks = g & 7, nt2 = g >> 3;
        const int k = ks * 32 + (lane >> 4) * 8 + j;   // hidden
        const int c = nt2 * 16 + (lane & 15);          // out
        wsf[W2F_OFF + tid2] = (f16)W2[k * OUTD + c];   // B-frag for stage B
    }
}

__global__ void count_nodes(const int* __restrict__ batch, int* __restrict__ cnt) {
    const int n = blockIdx.x * blockDim.x + threadIdx.x;
    if (n < NN) atomicAdd(&cnt[batch[n]], 1);
}

__global__ void build_desc(const int* __restrict__ cnt,
                           int* __restrict__ cursor,
                           unsigned* __restrict__ desc) {
    __shared__ int sc[256], sb[256];
    const int t = threadIdx.x;
    const int c  = cnt[t];
    const int nb = (c + 63) >> 6;
    sc[t] = c;  sb[t] = nb;
    __syncthreads();
    #pragma unroll
    for (int o = 1; o < 256; o <<= 1) {                // Hillis-Steele inclusive
        const int vc = (t >= o) ? sc[t - o] : 0;
        const int vb = (t >= o) ? sb[t - o] : 0;
        __syncthreads();
        sc[t] += vc;  sb[t] += vb;
        __syncthreads();
    }
    const int off  = sc[t] - c;                        // exclusive node offset
    const int boff = sb[t] - nb;                       // exclusive block offset
    cursor[t] = off;
    for (int i = t; i < DESC_MAX; i += 256) desc[i] = 0;   // sentinel cnt=0
    __syncthreads();
    for (int j = 0; j < nb; ++j) {
        const int st = off + j * 64;
        const int cn = min(64, c - j * 64);
        desc[boff + j] = ((unsigned)t << 24) | ((unsigned)cn << 17) | (unsigned)st;
    }
}

__global__ void scatter_nodes(const int* __restrict__ batch,
                              int* __restrict__ cursor,
                              int* __restrict__ perm) {
    const int n = blockIdx.x * blockDim.x + threadIdx.x;
    if (n < NN) {
        const int slot = atomicAdd(&cursor[batch[n]], 1);
        perm[slot] = n;
    }
}

__global__ __launch_bounds__(BLOCK, 7)
void gnn_decoder(const float* __restrict__ z,      // [B, K, LATENT] fp32
                 const float* __restrict__ s,      // [N, K] fp32
                 const f16*   __restrict__ wsf,    // swizzled f16 weights
                 const unsigned* __restrict__ desc,
                 const int*   __restrict__ perm,
                 const float* __restrict__ b1,
                 const float* __restrict__ b2,
                 float*       __restrict__ out)    // [N, OUT] fp32
{
    __shared__ f16 zf[4][64][8];        // 4 KB: z[b] B-frags, 4 l-tiles
    __shared__ f16 latlds[4][64][20];   // 10 KB: per-wave lat[l][node] (pad 20)
    __shared__ f16 hcf[4][2][64][8];    // 8 KB: relu(h) A-frags, per-wave dbuf

    const unsigned d = desc[blockIdx.x];
    const int cnt = (d >> 17) & 127;
    if (cnt == 0) return;                              // uniform: whole block
    const int bg    = d >> 24;
    const int start = d & 0x1FFFF;

    const int t    = threadIdx.x;
    const int w    = t >> 6;
    const int lane = t & 63;
    const int lrow = lane & 15;
    const int quad = lane >> 4;

    // ---- stage zf: wave w builds l-tile w; 8 scalar loads from 8KB L2-hot --
    {
        const float* zb = z + (size_t)bg * (KK * LATENT) + quad * 8 * LATENT
                        + w * 16 + lrow;
        f16x8 v;
        #pragma unroll
        for (int j = 0; j < 8; ++j) v[j] = (f16)zb[j * LATENT];
        *(f16x8*)&zf[w][lane][0] = v;                  // b128, lane-linear
    }

    // ---- s A-frag: node = start + w*16 + lrow (clamped), k = quad*8..+8 ----
    const int slot_l = w * 16 + lrow;
    const int pn = perm[start + (slot_l < cnt ? slot_l : 0)];
    f16x8 sA;
    {
        const float4* sp = (const float4*)(s + (size_t)pn * KK + quad * 8);
        const float4 s0 = sp[0], s1 = sp[1];
        sA[0] = (f16)s0.x; sA[1] = (f16)s0.y; sA[2] = (f16)s0.z; sA[3] = (f16)s0.w;
        sA[4] = (f16)s1.x; sA[5] = (f16)s1.y; sA[6] = (f16)s1.z; sA[7] = (f16)s1.w;
    }
    __syncthreads();                                   // zf ready (only barrier)

    // ---- phase 0b: lat = s @ z[b] (K=32), one MFMA per 16-col l-tile -------
    // D: col(lane&15)=l-col, row(quad*4+r)=node-local. Transpose via latlds.
    #pragma unroll
    for (int lt = 0; lt < 4; ++lt) {
        const f16x8 zB = *(const f16x8*)&zf[lt][lane][0];
        f32x4 D = (f32x4){0.f, 0.f, 0.f, 0.f};
        D = __builtin_amdgcn_mfma_f32_16x16x32_f16(sA, zB, D, 0, 0, 0);
        f16x4 dv;
        #pragma unroll
        for (int r = 0; r < 4; ++r) dv[r] = (f16)D[r];
        // latlds[w][l = lt*16+lrow][node = quad*4 .. +4]
        *(f16x4*)&latlds[w][lt * 16 + lrow][quad * 4] = dv;   // one b64
    }
    __builtin_amdgcn_wave_barrier();

    // ---- gather lat B-frags: B[k=quad*8+j][n=lrow], k += ks*32 -------------
    f16x8 latB0, latB1;
    #pragma unroll
    for (int j = 0; j < 8; ++j) {
        latB0[j] = latlds[w][quad * 8 + j][lrow];
        latB1[j] = latlds[w][32 + quad * 8 + j][lrow];
    }

    // ---- fused stages A+B (R5 verified, per-wave, barrier-free) ------------
    const f16x8*  W1f = (const f16x8*)wsf;
    const f16x8*  W2f = (const f16x8*)(wsf + W2F_OFF);
    const float4* b1v = (const float4*)b1;

    f32x4 O0 = (f32x4){0.f, 0.f, 0.f, 0.f};
    f32x4 O1 = (f32x4){0.f, 0.f, 0.f, 0.f};

    #pragma unroll
    for (int ksH = 0; ksH < 8; ++ksH) {
        #pragma unroll
        for (int p = 0; p < 2; ++p) {
            const int ntA = ksH * 2 + p;
            f32x4 C = (f32x4){0.f, 0.f, 0.f, 0.f};
            C = __builtin_amdgcn_mfma_f32_16x16x32_f16(
                    W1f[(ntA * 2 + 0) * 64 + lane], latB0, C, 0, 0, 0);
            C = __builtin_amdgcn_mfma_f32_16x16x32_f16(
                    W1f[(ntA * 2 + 1) * 64 + lane], latB1, C, 0, 0, 0);
            const float4 bq = b1v[ntA * 4 + quad];
            f16x4 hv;
            hv[0] = (f16)fmaxf(C[0] + bq.x, 0.f);
            hv[1] = (f16)fmaxf(C[1] + bq.y, 0.f);
            hv[2] = (f16)fmaxf(C[2] + bq.z, 0.f);
            hv[3] = (f16)fmaxf(C[3] + bq.w, 0.f);
            *(f16x4*)&hcf[w][ksH & 1][(p * 2 + (quad >> 1)) * 16 + lrow][(quad & 1) * 4] = hv;
        }
        __builtin_amdgcn_wave_barrier();
        const f16x8 Ah = *(const f16x8*)&hcf[w][ksH & 1][lane][0];
        O0 = __builtin_amdgcn_mfma_f32_16x16x32_f16(Ah, W2f[(0 * 8 + ksH) * 64 + lane], O0, 0, 0, 0);
        O1 = __builtin_amdgcn_mfma_f32_16x16x32_f16(Ah, W2f[(1 * 8 + ksH) * 64 + lane], O1, 0, 0, 0);
    }

    // ---- epilogue: +b2, scatter-store via perm (64B/quad-row sectors) ------
    {
        int pnr[4];
        #pragma unroll
        for (int r = 0; r < 4; ++r) {
            const int m = w * 16 + quad * 4 + r;
            pnr[r] = (m < cnt) ? perm[start + m] : -1;
        }
        const float b2a = b2[lrow];
        const float b2b = b2[16 + lrow];
        #pragma unroll
        for (int r = 0; r < 4; ++r) {
            if (pnr[r] >= 0) {
                float* dst = out + (size_t)pnr[r] * OUTD;
                dst[lrow]      = O0[r] + b2a;
                dst[16 + lrow] = O1[r] + b2b;
            }
        }
    }
}

extern "C" void kernel_launch(void* const* d_in, const int* in_sizes, int n_in,
                              void* d_out, int out_size, void* d_ws, size_t ws_size,
                              hipStream_t stream) {
    const float* z     = (const float*)d_in[0];
    const float* s     = (const float*)d_in[1];
    const int*   batch = (const int*)d_in[2];
    const float* W1    = (const float*)d_in[3];
    const float* b1    = (const float*)d_in[4];
    const float* W2    = (const float*)d_in[5];
    const float* b2    = (const float*)d_in[6];
    float* out = (float*)d_out;

    f16*      wsf    = (f16*)d_ws;                          // 48 KB
    int*      cnt    = (int*)((char*)d_ws + 49152);         // 256
    int*      cursor = cnt + 256;                           // 256
    unsigned* desc   = (unsigned*)(cursor + 256);           // 2048 slots
    int*      perm   = (int*)(desc + 2048);                 // 100000

    convert_weights<<<96, 256, 0, stream>>>(W1, W2, wsf, cnt);
    count_nodes<<<(NN + 255) / 256, 256, 0, stream>>>(batch, cnt);
    build_desc<<<1, 256, 0, stream>>>(cnt, cursor, desc);
    scatter_nodes<<<(NN + 255) / 256, 256, 0, stream>>>(batch, cursor, perm);
    gnn_decoder<<<DESC_MAX, BLOCK, 0, stream>>>(z, s, wsf, desc, perm, b1, b2, out);
}

// Round 7
// 107.524 us; speedup vs baseline: 1.8254x; 1.8254x over previous
//
#include <hip/hip_runtime.h>
#include <hip/hip_fp16.h>

// GNNDecoder: out = relu((einsum("nk,nkl->nl", s, z[batch])) @ W1 + b1) @ W2 + b2
// N=100000, B=256, K=32, LATENT=64, HIDDEN=256, OUT=32. fp32 in/out.
//
// R6 post-mortem: decoder fixed (off the top-5), but count+scatter each burn
// ~48us on 100k device-scope atomicAdds into 256 lines. R7: fixed-stride
// buckets perm[256][512] (max bucket ~390+6sigma<512) -> no scan, no desc;
// ONE fused scatter kernel: per-block LDS histogram for local slots, then
// <=256 global atomics/block (25k total vs 200k serialized) reserving ranges
// in cnt[] (cursor==final count). 5 launches -> 3. Decoder identical to R6
// (HW-verified) except (graph,chunk) indexing off blockIdx.
// Frag maps (HW-verified R4/R5): A[m=lane&15][k=quad*8+j],
// B[k=quad*8+j][n=lane&15], C/D col=lane&15 row=quad*4+reg.

using f16   = _Float16;
using f16x4 = __attribute__((ext_vector_type(4))) _Float16;
using f16x8 = __attribute__((ext_vector_type(8))) _Float16;
using f32x4 = __attribute__((ext_vector_type(4))) float;

constexpr int NN     = 100000;
constexpr int KK     = 32;
constexpr int LATENT = 64;
constexpr int HIDDEN = 256;
constexpr int OUTD   = 32;

constexpr int BLOCK = 256;       // decoder: 4 waves, 16 nodes/wave
constexpr int BSTRIDE = 512;     // perm bucket stride (max cnt ~460 w/ margin)
constexpr int W2F_OFF = 16384;   // f16 index of W2 frags in ws

// d_ws: [0,48K) f16 weights | cnt[256] | perm[256*512]  (~574 KB)

__global__ void convert_weights(const float* __restrict__ W1,
                                const float* __restrict__ W2,
                                f16* __restrict__ wsf,
                                int* __restrict__ cnt) {
    const int tid = blockIdx.x * blockDim.x + threadIdx.x;
    if (tid < 256) cnt[tid] = 0;                       // zero bucket cursors
    if (tid < 16384) {
        const int j = tid & 7, lane = (tid >> 3) & 63, g = tid >> 9;
        const int ks = g & 1, nt = g >> 1;
        const int k = ks * 32 + (lane >> 4) * 8 + j;   // latent
        const int c = nt * 16 + (lane & 15);           // hidden
        wsf[tid] = (f16)W1[k * HIDDEN + c];            // stage-A A-frag
    } else if (tid < 16384 + 8192) {
        const int tid2 = tid - 16384;
        const int j = tid2 & 7, lane = (tid2 >> 3) & 63, g = tid2 >> 9;
        const int ks = g & 7, nt2 = g >> 3;
        const int k = ks * 32 + (lane >> 4) * 8 + j;   // hidden
        const int c = nt2 * 16 + (lane & 15);          // out
        wsf[W2F_OFF + tid2] = (f16)W2[k * OUTD + c];   // stage-B B-frag
    }
}

// Fused count+scatter: LDS histogram -> <=256 global atomics per block.
__global__ __launch_bounds__(1024)
void scatter_nodes(const int* __restrict__ batch,
                   int* __restrict__ cnt,     // [256] cursor -> final counts
                   int* __restrict__ perm) {  // [256*BSTRIDE]
    __shared__ int lcnt[256];
    __shared__ int lbase[256];
    const int t = threadIdx.x;
    if (t < 256) lcnt[t] = 0;
    __syncthreads();
    const int n = blockIdx.x * 1024 + t;
    int b = 0, slot = -1;
    if (n < NN) {
        b = batch[n];
        slot = atomicAdd(&lcnt[b], 1);     // LDS atomic: local slot
    }
    __syncthreads();
    if (t < 256 && lcnt[t] > 0) lbase[t] = atomicAdd(&cnt[t], lcnt[t]);
    __syncthreads();
    if (slot >= 0) perm[(b << 9) + lbase[b] + slot] = n;
}

__global__ __launch_bounds__(BLOCK, 7)
void gnn_decoder(const float* __restrict__ z,      // [B, K, LATENT] fp32
                 const float* __restrict__ s,      // [N, K] fp32
                 const f16*   __restrict__ wsf,    // swizzled f16 weights
                 const int*   __restrict__ cnt,    // [256] bucket counts
                 const int*   __restrict__ perm,   // [256*BSTRIDE]
                 const float* __restrict__ b1,
                 const float* __restrict__ b2,
                 float*       __restrict__ out)    // [N, OUT] fp32
{
    __shared__ f16 zf[4][64][8];        // 4 KB: z[b] B-frags, 4 l-tiles
    __shared__ f16 latlds[4][64][20];   // 10 KB: per-wave lat[l][node] (pad 20)
    __shared__ f16 hcf[4][2][64][8];    // 8 KB: relu(h) A-frags, per-wave dbuf

    const int bg    = blockIdx.x >> 3;          // graph
    const int chunk = blockIdx.x & 7;           // 64-node chunk within graph
    const int cnt_c = cnt[bg] - chunk * 64;
    if (cnt_c <= 0) return;                     // uniform: whole block exits
    const int cn    = cnt_c < 64 ? cnt_c : 64;  // nodes in this chunk
    const int start = (bg << 9) + chunk * 64;   // perm base

    const int t    = threadIdx.x;
    const int w    = t >> 6;
    const int lane = t & 63;
    const int lrow = lane & 15;
    const int quad = lane >> 4;

    // ---- stage zf: wave w builds l-tile w from L2-hot 8KB z[bg] ------------
    {
        const float* zb = z + (size_t)bg * (KK * LATENT) + quad * 8 * LATENT
                        + w * 16 + lrow;
        f16x8 v;
        #pragma unroll
        for (int j = 0; j < 8; ++j) v[j] = (f16)zb[j * LATENT];
        *(f16x8*)&zf[w][lane][0] = v;           // b128, lane-linear
    }

    // ---- s A-frag: node = start + w*16 + lrow (clamped), k = quad*8..+8 ----
    const int slot_l = w * 16 + lrow;
    const int pn = perm[start + (slot_l < cn ? slot_l : 0)];
    f16x8 sA;
    {
        const float4* sp = (const float4*)(s + (size_t)pn * KK + quad * 8);
        const float4 s0 = sp[0], s1 = sp[1];
        sA[0] = (f16)s0.x; sA[1] = (f16)s0.y; sA[2] = (f16)s0.z; sA[3] = (f16)s0.w;
        sA[4] = (f16)s1.x; sA[5] = (f16)s1.y; sA[6] = (f16)s1.z; sA[7] = (f16)s1.w;
    }
    __syncthreads();                            // zf ready (only barrier)

    // ---- phase 0b: lat = s @ z[bg] (K=32), one MFMA per 16-col l-tile ------
    #pragma unroll
    for (int lt = 0; lt < 4; ++lt) {
        const f16x8 zB = *(const f16x8*)&zf[lt][lane][0];
        f32x4 D = (f32x4){0.f, 0.f, 0.f, 0.f};
        D = __builtin_amdgcn_mfma_f32_16x16x32_f16(sA, zB, D, 0, 0, 0);
        f16x4 dv;
        #pragma unroll
        for (int r = 0; r < 4; ++r) dv[r] = (f16)D[r];
        *(f16x4*)&latlds[w][lt * 16 + lrow][quad * 4] = dv;   // one b64
    }
    __builtin_amdgcn_wave_barrier();

    // ---- gather lat B-frags: B[k=quad*8+j][n=lrow], k += ks*32 -------------
    f16x8 latB0, latB1;
    #pragma unroll
    for (int j = 0; j < 8; ++j) {
        latB0[j] = latlds[w][quad * 8 + j][lrow];
        latB1[j] = latlds[w][32 + quad * 8 + j][lrow];
    }

    // ---- fused stages A+B (HW-verified R5/R6, per-wave, barrier-free) ------
    const f16x8*  W1f = (const f16x8*)wsf;
    const f16x8*  W2f = (const f16x8*)(wsf + W2F_OFF);
    const float4* b1v = (const float4*)b1;

    f32x4 O0 = (f32x4){0.f, 0.f, 0.f, 0.f};
    f32x4 O1 = (f32x4){0.f, 0.f, 0.f, 0.f};

    #pragma unroll
    for (int ksH = 0; ksH < 8; ++ksH) {
        #pragma unroll
        for (int p = 0; p < 2; ++p) {
            const int ntA = ksH * 2 + p;
            f32x4 C = (f32x4){0.f, 0.f, 0.f, 0.f};
            C = __builtin_amdgcn_mfma_f32_16x16x32_f16(
                    W1f[(ntA * 2 + 0) * 64 + lane], latB0, C, 0, 0, 0);
            C = __builtin_amdgcn_mfma_f32_16x16x32_f16(
                    W1f[(ntA * 2 + 1) * 64 + lane], latB1, C, 0, 0, 0);
            const float4 bq = b1v[ntA * 4 + quad];
            f16x4 hv;
            hv[0] = (f16)fmaxf(C[0] + bq.x, 0.f);
            hv[1] = (f16)fmaxf(C[1] + bq.y, 0.f);
            hv[2] = (f16)fmaxf(C[2] + bq.z, 0.f);
            hv[3] = (f16)fmaxf(C[3] + bq.w, 0.f);
            *(f16x4*)&hcf[w][ksH & 1][(p * 2 + (quad >> 1)) * 16 + lrow][(quad & 1) * 4] = hv;
        }
        __builtin_amdgcn_wave_barrier();
        const f16x8 Ah = *(const f16x8*)&hcf[w][ksH & 1][lane][0];
        O0 = __builtin_amdgcn_mfma_f32_16x16x32_f16(Ah, W2f[(0 * 8 + ksH) * 64 + lane], O0, 0, 0, 0);
        O1 = __builtin_amdgcn_mfma_f32_16x16x32_f16(Ah, W2f[(1 * 8 + ksH) * 64 + lane], O1, 0, 0, 0);
    }

    // ---- epilogue: +b2, scatter-store via perm (64B/quad-row sectors) ------
    {
        int pnr[4];
        #pragma unroll
        for (int r = 0; r < 4; ++r) {
            const int m = w * 16 + quad * 4 + r;
            pnr[r] = (m < cn) ? perm[start + m] : -1;
        }
        const float b2a = b2[lrow];
        const float b2b = b2[16 + lrow];
        #pragma unroll
        for (int r = 0; r < 4; ++r) {
            if (pnr[r] >= 0) {
                float* dst = out + (size_t)pnr[r] * OUTD;
                dst[lrow]      = O0[r] + b2a;
                dst[16 + lrow] = O1[r] + b2b;
            }
        }
    }
}

extern "C" void kernel_launch(void* const* d_in, const int* in_sizes, int n_in,
                              void* d_out, int out_size, void* d_ws, size_t ws_size,
                              hipStream_t stream) {
    const float* z     = (const float*)d_in[0];
    const float* s     = (const float*)d_in[1];
    const int*   batch = (const int*)d_in[2];
    const float* W1    = (const float*)d_in[3];
    const float* b1    = (const float*)d_in[4];
    const float* W2    = (const float*)d_in[5];
    const float* b2    = (const float*)d_in[6];
    float* out = (float*)d_out;

    f16* wsf  = (f16*)d_ws;                          // 48 KB
    int* cnt  = (int*)((char*)d_ws + 49152);         // 256
    int* perm = cnt + 256;                           // 256*512

    convert_weights<<<96, 256, 0, stream>>>(W1, W2, wsf, cnt);
    scatter_nodes<<<(NN + 1023) / 1024, 1024, 0, stream>>>(batch, cnt, perm);
    gnn_decoder<<<256 * 8, BLOCK, 0, stream>>>(z, s, wsf, cnt, perm, b1, b2, out);
}